// Round 1
// 486.936 us; speedup vs baseline: 1.0755x; 1.0755x over previous
//
#include <hip/hip_runtime.h>
#include <stdint.h>

#define H 512
#define W 512
#define HW (H * W)
#define NIMG 128
#define AX 26214
#define NB 8192
#define CAND_CAP 7168

__device__ __forceinline__ float4 f4zero() { return make_float4(0.f, 0.f, 0.f, 0.f); }

// Find bin b such that suffix_excl(b) < K <= suffix_excl(b) + hist[b].
// Block = 1024 threads; only tid<512 do per-chunk work (16 bins each); all
// threads hit the barriers. hist has NB=8192 bins. LDS layout unchanged.
__device__ __forceinline__ void block_select(uint32_t* hist, uint32_t* chunkSuf,
                                             uint32_t* outBin, uint32_t* outRank,
                                             uint32_t K) {
  int tid = threadIdx.x;
  if (tid < 512) {
    int base = tid * 16;
    uint32_t csum = 0;
#pragma unroll
    for (int k = 0; k < 16; k++) csum += hist[base + k];
    chunkSuf[tid] = csum;
  }
  __syncthreads();
  if (tid < 64) {
    uint32_t cs[8];
    uint32_t g = 0;
#pragma unroll
    for (int m = 0; m < 8; m++) { cs[m] = chunkSuf[tid * 8 + m]; g += cs[m]; }
    uint32_t v = g;
#pragma unroll
    for (int off = 1; off < 64; off <<= 1) {
      uint32_t u = __shfl_down(v, off);
      if (tid + off < 64) v += u;
    }
    uint32_t run = v - g;
    for (int m = 7; m >= 0; m--) {
      chunkSuf[tid * 8 + m] = run;
      run += cs[m];
    }
  }
  __syncthreads();
  if (tid < 512) {
    int base = tid * 16;
    uint32_t run = chunkSuf[tid];
    for (int k = 15; k >= 0; k--) {
      uint32_t h = hist[base + k];
      if (run < K && run + h >= K) {
        *outBin = (uint32_t)(base + k);
        *outRank = K - run;
      }
      run += h;
    }
  }
  __syncthreads();
}

// PASS 0: histogram of squared-mag bits >> 19.  PASS 1: compact matching bin.
// 1024 threads: tid&127 = column group (4 cols), tid>>7 = row strip (64 rows).
// Depth-3 row pipeline: rows r+2, r+3 in flight while computing row r.
template <int PASS>
__device__ __forceinline__ void select_pass(const float* __restrict__ x,
                                            uint32_t* hist, uint32_t* cand,
                                            uint32_t* sCnt, uint32_t b0) {
  int tid = threadIdx.x;
  int wl = tid & 63;
  int lane_c = (tid & 127) << 2;
  int r0 = (tid >> 7) << 6;  // 8 strips x 64 rows
  const bool haveE = lane_c + 4 < W;

  float4 vA, vB, vC, vD;
  float eA = 0.f, eB = 0.f, eC = 0.f, eD = 0.f;
#define LDROW(r, v, e)                                        \
  {                                                           \
    if ((r) < H) {                                            \
      v = *(const float4*)(x + (r) * W + lane_c);             \
      if (wl == 63) e = haveE ? x[(r) * W + lane_c + 4] : 0.f;\
    } else { v = f4zero(); e = 0.f; }                         \
  }
  LDROW(r0, vA, eA)
  LDROW(r0 + 1, vB, eB)
  LDROW(r0 + 2, vC, eC)
  for (int it = 0; it < 64; ++it) {
    int r = r0 + it;
    if (it < 62) { LDROW(r + 3, vD, eD) } else { vD = f4zero(); eD = 0.f; }
    float ea = __shfl(vA.x, wl + 1); if (wl == 63) ea = eA;
    float eb = __shfl(vB.x, wl + 1); if (wl == 63) eb = eB;
    float a[5] = {vA.x, vA.y, vA.z, vA.w, ea};
    float bb[5] = {vB.x, vB.y, vB.z, vB.w, eb};
#pragma unroll
    for (int j = 0; j < 4; j++) {
      float g0 = a[j] - bb[j + 1];
      float g1 = a[j + 1] - bb[j];
      float msq = fmaf(g0, g0, fmaf(g1, g1, 1e-12f));
      uint32_t bits = __float_as_uint(msq);
      if (PASS == 0) {
        atomicAdd(&hist[bits >> 19], 1u);
      } else {
        if ((bits >> 19) == b0) {
          uint32_t idx = atomicAdd(sCnt, 1u);
          if (idx < CAND_CAP) cand[idx] = bits;
        }
      }
    }
    vA = vB; eA = eB; vB = vC; eB = eC; vC = vD; eC = eD;
  }
#undef LDROW
}

// One block per (tensor, image): exact rank-AX threshold (squared domain,
// sqrt-free) via radix select on float bits. 1024 thr -> 16 waves/CU.
__global__ __launch_bounds__(1024) void selectKernel(const float* __restrict__ target,
                                                     const float* __restrict__ pred,
                                                     float* __restrict__ thr) {
  __shared__ uint32_t hist[NB];        // 32 KB
  __shared__ uint32_t cand[CAND_CAP];  // 28 KB
  __shared__ uint32_t chunkSuf[512];   // 2 KB
  __shared__ uint32_t sBin, sRank, sCnt;
  int tid = threadIdx.x;
  int b = blockIdx.x;
  int img = b & 127;
  const float* __restrict__ x = ((b >> 7) ? pred : target) + (size_t)img * HW;

  for (int i = tid; i < NB; i += 1024) hist[i] = 0;
  if (tid == 0) { sBin = 0; sRank = 1; sCnt = 0; }
  __syncthreads();

  select_pass<0>(x, hist, cand, &sCnt, 0);
  __syncthreads();
  block_select(hist, chunkSuf, &sBin, &sRank, AX);
  uint32_t b0 = sBin;
  uint32_t K1 = sRank;
  __syncthreads();

  select_pass<1>(x, hist, cand, &sCnt, b0);
  __syncthreads();
  uint32_t cnt = sCnt;
  if (cnt > CAND_CAP) cnt = CAND_CAP;  // expected ~3.3K; cap far in the tail

  // Mini-round 1: next 13 bits, in-LDS
  for (int i = tid; i < NB; i += 1024) hist[i] = 0;
  __syncthreads();
  for (uint32_t j = tid; j < cnt; j += 1024)
    atomicAdd(&hist[(cand[j] >> 6) & 0x1FFFu], 1u);
  __syncthreads();
  block_select(hist, chunkSuf, &sBin, &sRank, K1);
  uint32_t b1 = sBin;
  uint32_t K2 = sRank;
  __syncthreads();

  // Mini-round 2: last 6 bits
  for (int i = tid; i < NB; i += 1024) hist[i] = 0;
  __syncthreads();
  for (uint32_t j = tid; j < cnt; j += 1024) {
    uint32_t bits = cand[j];
    if (((bits >> 6) & 0x1FFFu) == b1) atomicAdd(&hist[bits & 63u], 1u);
  }
  __syncthreads();
  block_select(hist, chunkSuf, &sBin, &sRank, K2);
  if (tid == 0) {
    uint32_t tb = (b0 << 19) | (b1 << 6) | sBin;
    thr[b] = __uint_as_float(tb);  // SQUARED threshold bits
  }
}

// Per-position sequential carry over images. Thread = 1 col x 1 row (scalar
// loads, 256 B/wave coalesced); depth-2 image pipeline; col+1 via shfl
// (lane63 scalar). Block = 512 thr = 1 row; 512 blocks -> 2 blocks/CU =
// 16 waves/CU. XCD swizzle: 64 contiguous rows per XCD so row r+1 (also
// loaded by block r+1) is an L2 hit on the same XCD.
__global__ __launch_bounds__(512, 4) void scanKernel(const float* __restrict__ target,
                                                     const float* __restrict__ pred,
                                                     const float* __restrict__ thr,
                                                     double* __restrict__ sum) {
  __shared__ float sT[NIMG], sP[NIMG];
  __shared__ float ws8[8];
  int tid = threadIdx.x;
  if (tid < NIMG) { sT[tid] = thr[tid]; sP[tid] = thr[NIMG + tid]; }
  __syncthreads();
  int b = blockIdx.x;
  int r = ((b & 7) << 6) + (b >> 3);  // XCD-contiguous rows
  int c = tid;
  int wl = tid & 63;
  const bool haveB = r + 1 < H;       // block-uniform
  const bool edgeL = (wl == 63);
  const bool haveE = c + 1 < W;
  size_t offA = (size_t)r * W + c;
  size_t offB = offA + W;

  float tA[2], tB[2], pA[2], pB[2];
  float eT[2], eU[2], eP[2], eQ[2];

#define LOADI(i, buf)                                             \
  {                                                               \
    const float* xt = target + (size_t)(i) * HW;                  \
    const float* xp = pred + (size_t)(i) * HW;                    \
    tA[buf] = xt[offA];                                           \
    pA[buf] = xp[offA];                                           \
    tB[buf] = haveB ? xt[offB] : 0.f;                             \
    pB[buf] = haveB ? xp[offB] : 0.f;                             \
    eT[buf] = 0.f; eU[buf] = 0.f; eP[buf] = 0.f; eQ[buf] = 0.f;   \
    if (edgeL) {                                                  \
      eT[buf] = haveE ? xt[offA + 1] : 0.f;                       \
      eP[buf] = haveE ? xp[offA + 1] : 0.f;                       \
      eU[buf] = (haveE && haveB) ? xt[offB + 1] : 0.f;            \
      eQ[buf] = (haveE && haveB) ? xp[offB + 1] : 0.f;            \
    }                                                             \
  }

  float etf = 0.f, epf = 0.f, acc = 0.f;
  LOADI(0, 0)
#pragma unroll 2
  for (int i = 0; i < NIMG; ++i) {
    int cb = i & 1;
    if (i + 1 < NIMG) LOADI(i + 1, cb ^ 1)
    float tsqT = sT[i], tsqP = sP[i];
    float a1 = __shfl(tA[cb], wl + 1); if (edgeL) a1 = eT[cb];
    float b1 = __shfl(tB[cb], wl + 1); if (edgeL) b1 = eU[cb];
    float p1 = __shfl(pA[cb], wl + 1); if (edgeL) p1 = eP[cb];
    float q1 = __shfl(pB[cb], wl + 1); if (edgeL) q1 = eQ[cb];
    float g0 = tA[cb] - b1;           // x[r][c]   - x[r+1][c+1]
    float g1 = a1 - tB[cb];           // x[r][c+1] - x[r+1][c]
    float msq = fmaf(g0, g0, fmaf(g1, g1, 1e-12f));
    if (msq >= tsqT) etf = sqrtf(msq);
    g0 = pA[cb] - q1;
    g1 = p1 - pB[cb];
    float msp = fmaf(g0, g0, fmaf(g1, g1, 1e-12f));
    if (msp >= tsqP) epf = sqrtf(msp);
    acc += fabsf((etf - epf) / (etf + epf + 1e-5f));
  }
#undef LOADI

  for (int off = 32; off; off >>= 1) acc += __shfl_down(acc, off);
  if (wl == 0) ws8[tid >> 6] = acc;
  __syncthreads();
  if (tid == 0) {
    double s = 0.0;
#pragma unroll
    for (int k = 0; k < 8; k++) s += (double)ws8[k];
    atomicAdd(sum, s);
  }
}

__global__ void initKernel(double* __restrict__ sum) { *sum = 0.0; }

__global__ void finalKernel(const double* __restrict__ sum,
                            const float* __restrict__ alpha,
                            float* __restrict__ out) {
  out[0] = (float)((double)alpha[0] * (sum[0] / (double)((double)NIMG * (double)HW)));
}

extern "C" void kernel_launch(void* const* d_in, const int* in_sizes, int n_in,
                              void* d_out, int out_size, void* d_ws, size_t ws_size,
                              hipStream_t stream) {
  const float* pred = (const float*)d_in[0];    // predictions [16,8,512,512]
  const float* target = (const float*)d_in[1];  // target      [16,8,512,512]
  const float* alpha = (const float*)d_in[2];   // scalar
  // d_in[3] = Roberts kernels (fixed values, hardcoded)

  double* d_sum = (double*)d_ws;
  float* d_thr = (float*)((char*)d_ws + 64);  // 256 floats (squared-threshold bits)

  initKernel<<<1, 1, 0, stream>>>(d_sum);
  selectKernel<<<256, 1024, 0, stream>>>(target, pred, d_thr);
  scanKernel<<<512, 512, 0, stream>>>(target, pred, d_thr, d_sum);
  finalKernel<<<1, 1, 0, stream>>>(d_sum, alpha, (float*)d_out);
}

// Round 2
// 408.565 us; speedup vs baseline: 1.2818x; 1.1918x over previous
//
#include <hip/hip_runtime.h>
#include <stdint.h>

#define H 512
#define W 512
#define HW (H * W)
#define NIMG 128
#define AX 26214
#define NB 8192
#define CAP 12288
#define KS 3277   // ~AX/8 (sampled rank)
#define KM 240    // 4.4 sigma bracket margin
#define SMEM_WORDS (NB + CAP + 512 + 4)
#define SMEM_BYTES (SMEM_WORDS * 4)

__device__ __forceinline__ float4 f4zero() { return make_float4(0.f, 0.f, 0.f, 0.f); }

// Find bin b such that suffix_excl(b) < K <= suffix_excl(b) + hist[b]
// (rank K from the top / highest bins). Block = 1024 thr; tid<512 own 16 bins.
__device__ __forceinline__ void block_select(uint32_t* hist, uint32_t* chunkSuf,
                                             volatile uint32_t* outBin,
                                             volatile uint32_t* outRank, uint32_t K) {
  int tid = threadIdx.x;
  if (tid < 512) {
    int base = tid * 16;
    uint32_t csum = 0;
#pragma unroll
    for (int k = 0; k < 16; k++) csum += hist[base + k];
    chunkSuf[tid] = csum;
  }
  __syncthreads();
  if (tid < 64) {
    uint32_t cs[8];
    uint32_t g = 0;
#pragma unroll
    for (int m = 0; m < 8; m++) { cs[m] = chunkSuf[tid * 8 + m]; g += cs[m]; }
    uint32_t v = g;
#pragma unroll
    for (int off = 1; off < 64; off <<= 1) {
      uint32_t u = __shfl_down(v, off);
      if (tid + off < 64) v += u;
    }
    uint32_t run = v - g;
    for (int m = 7; m >= 0; m--) {
      chunkSuf[tid * 8 + m] = run;
      run += cs[m];
    }
  }
  __syncthreads();
  if (tid < 512) {
    int base = tid * 16;
    uint32_t run = chunkSuf[tid];
    for (int k = 15; k >= 0; k--) {
      uint32_t h = hist[base + k];
      if (run < K && run + h >= K) {
        *outBin = (uint32_t)(base + k);
        *outRank = K - run;
      }
      run += h;
    }
  }
  __syncthreads();
}

// Sampled histogram: rows r ≡ 0 (mod 8). Each thread: 8 sampled rows x 4 cols.
// All sampled rows r in [0,504], r+1 <= 505 -> no row bounds checks needed.
__device__ __forceinline__ void sample_pass(const float* __restrict__ x,
                                            uint32_t* hist) {
  int tid = threadIdx.x;
  int lane_c = (tid & 127) << 2;
  int r0 = (tid >> 7) << 6;
  const bool haveE = lane_c + 4 < W;
  const float* xc = x + lane_c;
  float4 uA[2], uB[2];
  float fA[2], fB[2];
#define LDS2(k, buf)                                      \
  {                                                       \
    const float* rp = xc + (size_t)(r0 + 8 * (k)) * W;    \
    uA[buf] = *(const float4*)rp;                         \
    fA[buf] = haveE ? rp[4] : 0.f;                        \
    uB[buf] = *(const float4*)(rp + W);                   \
    fB[buf] = haveE ? rp[W + 4] : 0.f;                    \
  }
  LDS2(0, 0)
  for (int k = 0; k < 8; ++k) {
    int cb = k & 1;
    if (k < 7) LDS2(k + 1, cb ^ 1)
    float a[5] = {uA[cb].x, uA[cb].y, uA[cb].z, uA[cb].w, fA[cb]};
    float c[5] = {uB[cb].x, uB[cb].y, uB[cb].z, uB[cb].w, fB[cb]};
#pragma unroll
    for (int j = 0; j < 4; j++) {
      float g0 = a[j] - c[j + 1];
      float g1 = a[j + 1] - c[j];
      float msq = fmaf(g0, g0, fmaf(g1, g1, 1e-12f));
      atomicAdd(&hist[__float_as_uint(msq) >> 19], 1u);
    }
  }
#undef LDS2
}

// Full pass. HIST=1: histogram every position AND collect candidates whose
// bin is in [lo, lo+span]. HIST=0 (fallback): collect bin==lo only.
// Shfl-free: the 5th column element is a direct scalar load (same cache line).
// Depth-3 row pipeline.
template <int HIST>
__device__ __forceinline__ void full_pass(const float* __restrict__ x,
                                          uint32_t* hist, uint32_t* cand,
                                          uint32_t* sCnt, uint32_t lo,
                                          uint32_t span) {
  int tid = threadIdx.x;
  int lane_c = (tid & 127) << 2;
  int r0 = (tid >> 7) << 6;
  const bool haveE = lane_c + 4 < W;
  const float* xc = x + lane_c;

  float4 vA, vB, vC, vD;
  float eA = 0.f, eB = 0.f, eC = 0.f, eD = 0.f;
#define LDR(r, v, e)                                  \
  {                                                   \
    if ((r) < H) {                                    \
      const float* rp = xc + (size_t)(r) * W;         \
      v = *(const float4*)rp;                         \
      e = haveE ? rp[4] : 0.f;                        \
    } else { v = f4zero(); e = 0.f; }                 \
  }
  LDR(r0, vA, eA)
  LDR(r0 + 1, vB, eB)
  LDR(r0 + 2, vC, eC)
  for (int it = 0; it < 64; ++it) {
    int r = r0 + it;
    if (it < 62) { LDR(r + 3, vD, eD) } else { vD = f4zero(); eD = 0.f; }
    float a[5] = {vA.x, vA.y, vA.z, vA.w, eA};
    float c[5] = {vB.x, vB.y, vB.z, vB.w, eB};
#pragma unroll
    for (int j = 0; j < 4; j++) {
      float g0 = a[j] - c[j + 1];
      float g1 = a[j + 1] - c[j];
      float msq = fmaf(g0, g0, fmaf(g1, g1, 1e-12f));
      uint32_t bits = __float_as_uint(msq);
      uint32_t bin = bits >> 19;
      if (HIST) atomicAdd(&hist[bin], 1u);
      if (bin - lo <= span) {  // unsigned trick: lo <= bin <= lo+span
        uint32_t idx = atomicAdd(sCnt, 1u);
        if (idx < CAP) cand[idx] = bits;
      }
    }
    vA = vB; eA = eB; vB = vC; eB = eC; vC = vD; eC = eD;
  }
#undef LDR
}

// One block per (tensor, image). Sampled pilot brackets the threshold bin,
// then ONE full pass builds the exact histogram and collects candidates.
// Exact rank-AX threshold always (fallback pass if the bracket missed).
__global__ __launch_bounds__(1024) void selectKernel(const float* __restrict__ target,
                                                     const float* __restrict__ pred,
                                                     float* __restrict__ thr) {
  extern __shared__ uint32_t smem[];
  uint32_t* hist = smem;                           // NB
  uint32_t* cand = smem + NB;                      // CAP
  uint32_t* chunkSuf = smem + NB + CAP;            // 512
  volatile uint32_t* sBin = smem + NB + CAP + 512;
  volatile uint32_t* sRank = smem + NB + CAP + 513;
  uint32_t* sCnt = smem + NB + CAP + 514;

  int tid = threadIdx.x;
  int b = blockIdx.x;
  int img = b & 127;
  const float* __restrict__ x = ((b >> 7) ? pred : target) + (size_t)img * HW;

  for (int i = tid; i < NB; i += 1024) hist[i] = 0;
  if (tid == 0) *sCnt = 0;
  __syncthreads();

  // Phase A: sampled pilot -> bracket [bLo, bHi]
  sample_pass(x, hist);
  __syncthreads();
  block_select(hist, chunkSuf, sBin, sRank, KS - KM);
  uint32_t bHi = *sBin;
  block_select(hist, chunkSuf, sBin, sRank, KS + KM);
  uint32_t bLo = *sBin;
  __syncthreads();

  for (int i = tid; i < NB; i += 1024) hist[i] = 0;
  __syncthreads();

  // Phase B: the single full pass (histogram + ranged candidate collect)
  full_pass<1>(x, hist, cand, sCnt, bLo, bHi - bLo);
  __syncthreads();
  block_select(hist, chunkSuf, sBin, sRank, AX);
  uint32_t b0 = *sBin;
  uint32_t K1 = *sRank;
  uint32_t cnt = *sCnt;
  __syncthreads();

  // Fallback (rare): bracket missed or candidate overflow -> exact re-collect
  bool bad = (b0 < bLo) || (b0 > bHi) || (cnt > CAP);
  if (bad) {
    if (tid == 0) *sCnt = 0;
    __syncthreads();
    full_pass<0>(x, hist, cand, sCnt, b0, 0);
    __syncthreads();
    cnt = *sCnt;
    __syncthreads();
  }
  if (cnt > CAP) cnt = CAP;

  // Mini-round 1: next 13 bits (filter to bin b0)
  for (int i = tid; i < NB; i += 1024) hist[i] = 0;
  __syncthreads();
  for (uint32_t j = tid; j < cnt; j += 1024) {
    uint32_t bits = cand[j];
    if ((bits >> 19) == b0) atomicAdd(&hist[(bits >> 6) & 0x1FFFu], 1u);
  }
  __syncthreads();
  block_select(hist, chunkSuf, sBin, sRank, K1);
  uint32_t b1 = *sBin;
  uint32_t K2 = *sRank;
  __syncthreads();

  // Mini-round 2: last 6 bits
  for (int i = tid; i < NB; i += 1024) hist[i] = 0;
  __syncthreads();
  for (uint32_t j = tid; j < cnt; j += 1024) {
    uint32_t bits = cand[j];
    if ((bits >> 19) == b0 && ((bits >> 6) & 0x1FFFu) == b1)
      atomicAdd(&hist[bits & 63u], 1u);
  }
  __syncthreads();
  block_select(hist, chunkSuf, sBin, sRank, K2);
  if (tid == 0) {
    uint32_t tb = (b0 << 19) | (b1 << 6) | *sBin;
    thr[b] = __uint_as_float(tb);  // SQUARED threshold bits
  }
}

// Per-position sequential carry over images. Thread = 1 col x 1 row, all four
// stencil values loaded directly (no shfl -> no ds_bpermute on the critical
// path; +1 loads are L1 hits). Depth-2 image pipeline. 512 blocks x 512 thr =
// 2 blocks/CU = 16 waves/CU. XCD swizzle: 64 contiguous rows per XCD.
__global__ __launch_bounds__(512, 4) void scanKernel(const float* __restrict__ target,
                                                     const float* __restrict__ pred,
                                                     const float* __restrict__ thr,
                                                     double* __restrict__ sum) {
  __shared__ float sT[NIMG], sP[NIMG];
  __shared__ float ws8[8];
  int tid = threadIdx.x;
  if (tid < NIMG) { sT[tid] = thr[tid]; sP[tid] = thr[NIMG + tid]; }
  __syncthreads();
  int b = blockIdx.x;
  int r = ((b & 7) << 6) + (b >> 3);  // XCD-contiguous rows
  int c = tid;
  const bool haveB = r + 1 < H;  // block-uniform
  const bool haveE = c + 1 < W;
  size_t offA = (size_t)r * W + c;
  size_t offB = offA + W;

  float t00[2], t01[2], t10[2], t11[2];
  float p00[2], p01[2], p10[2], p11[2];

#define LOADI(i, buf)                                         \
  {                                                           \
    const float* xt = target + (size_t)(i) * HW;              \
    const float* xp = pred + (size_t)(i) * HW;                \
    t00[buf] = xt[offA];                                      \
    t01[buf] = haveE ? xt[offA + 1] : 0.f;                    \
    t10[buf] = haveB ? xt[offB] : 0.f;                        \
    t11[buf] = (haveB && haveE) ? xt[offB + 1] : 0.f;         \
    p00[buf] = xp[offA];                                      \
    p01[buf] = haveE ? xp[offA + 1] : 0.f;                    \
    p10[buf] = haveB ? xp[offB] : 0.f;                        \
    p11[buf] = (haveB && haveE) ? xp[offB + 1] : 0.f;         \
  }

  float etf = 0.f, epf = 0.f, acc = 0.f;
  LOADI(0, 0)
#pragma unroll 2
  for (int i = 0; i < NIMG; ++i) {
    int cb = i & 1;
    if (i + 1 < NIMG) LOADI(i + 1, cb ^ 1)
    float tsqT = sT[i], tsqP = sP[i];
    float g0 = t00[cb] - t11[cb];  // x[r][c]   - x[r+1][c+1]
    float g1 = t01[cb] - t10[cb];  // x[r][c+1] - x[r+1][c]
    float msq = fmaf(g0, g0, fmaf(g1, g1, 1e-12f));
    if (msq >= tsqT) etf = sqrtf(msq);
    g0 = p00[cb] - p11[cb];
    g1 = p01[cb] - p10[cb];
    float msp = fmaf(g0, g0, fmaf(g1, g1, 1e-12f));
    if (msp >= tsqP) epf = sqrtf(msp);
    acc += fabsf((etf - epf) / (etf + epf + 1e-5f));
  }
#undef LOADI

  for (int off = 32; off; off >>= 1) acc += __shfl_down(acc, off);
  if ((tid & 63) == 0) ws8[tid >> 6] = acc;
  __syncthreads();
  if (tid == 0) {
    double s = 0.0;
#pragma unroll
    for (int k = 0; k < 8; k++) s += (double)ws8[k];
    atomicAdd(sum, s);
  }
}

__global__ void initKernel(double* __restrict__ sum) { *sum = 0.0; }

__global__ void finalKernel(const double* __restrict__ sum,
                            const float* __restrict__ alpha,
                            float* __restrict__ out) {
  out[0] = (float)((double)alpha[0] * (sum[0] / (double)((double)NIMG * (double)HW)));
}

extern "C" void kernel_launch(void* const* d_in, const int* in_sizes, int n_in,
                              void* d_out, int out_size, void* d_ws, size_t ws_size,
                              hipStream_t stream) {
  const float* pred = (const float*)d_in[0];    // predictions [16,8,512,512]
  const float* target = (const float*)d_in[1];  // target      [16,8,512,512]
  const float* alpha = (const float*)d_in[2];   // scalar
  // d_in[3] = Roberts kernels (fixed values, hardcoded)

  double* d_sum = (double*)d_ws;
  float* d_thr = (float*)((char*)d_ws + 64);  // 256 floats (squared-threshold bits)

  static int attrSet = 0;
  if (!attrSet) {
    hipFuncSetAttribute(reinterpret_cast<const void*>(&selectKernel),
                        hipFuncAttributeMaxDynamicSharedMemorySize, SMEM_BYTES);
    attrSet = 1;
  }

  initKernel<<<1, 1, 0, stream>>>(d_sum);
  selectKernel<<<256, 1024, SMEM_BYTES, stream>>>(target, pred, d_thr);
  scanKernel<<<512, 512, 0, stream>>>(target, pred, d_thr, d_sum);
  finalKernel<<<1, 1, 0, stream>>>(d_sum, alpha, (float*)d_out);
}